// Round 12
// baseline (72.359 us; speedup 1.0000x reference)
//
#include <hip/hip_runtime.h>

// PillarLayer: fused copy + per-pillar xyz center-of-mass + BEV canvas scatter.
//
// R12 = R11 with the DS/MLP gradient pushed one more step:
//   8 lanes per pillar, 4 float4 per lane (r, r+8, r+16, r+24).
//   - load segments: 8 groups x 128B (full cache lines; R6's regression was
//     64B segments -- we stay at >=128B).
//   - butterfly: 3 steps x 3 comps = 9 ds_swizzle per wave covering 8 pillars
//     (1.1 DS/pillar vs R11's 3, R5's 22.5).
//   - MLP: 4 independent NT loads in flight per lane; 4KB per wave.
// Ladder: R5 (1KB contig, 22.5 DS/pillar) 76.7us -> R11 (4x256B, 3 DS/pillar)
// 72.1us -> R12 (8x128B, 1.1 DS/pillar).
//
// Inputs: d_in[0] pillars f32 (P,32,4); d_in[1] coors int32 (P,4) [b,x,y,z];
//         d_in[2] npoints int32 (P); d_in[3] bs; d_in[4] x_l; d_in[5] y_l.
// Output (concat f32): pillars copy | coors as f32 | npoints as f32 |
//         canvas (bs,3,y_l,x_l) with canvas[b][c][y][x] = center_c or 0.

typedef float vfloat4 __attribute__((ext_vector_type(4)));

__global__ __launch_bounds__(256) void canvas_zero(float4* __restrict__ dst, long n4) {
    long i = (long)blockIdx.x * blockDim.x + threadIdx.x;
    const long stride = (long)gridDim.x * blockDim.x;
    const float4 z = make_float4(0.f, 0.f, 0.f, 0.f);
    for (; i < n4; i += stride) dst[i] = z;   // cacheable: L3-resident for scatter
}

__global__ __launch_bounds__(256) void pillar_fused(
    const vfloat4* __restrict__ pillars4,  // P*32 (one float4 per point)
    const int4* __restrict__ coors4,       // P [b,x,y,z]
    const int* __restrict__ npoints,       // P
    const int* __restrict__ xlp,           // scalar x_l
    const int* __restrict__ ylp,           // scalar y_l
    vfloat4* __restrict__ out_pillars4,    // P*32
    float4* __restrict__ out_coors4,       // P
    float* __restrict__ out_np,            // P
    float* __restrict__ canvas,            // bs*3*y_l*x_l
    int P)
{
    const int tid = threadIdx.x;
    const int g   = tid >> 3;                  // pillar group within block (0..31)
    const int r   = tid & 7;                   // lane within pillar
    const int p   = blockIdx.x * 32 + g;       // pillar id (32 pillars/block)
    if (p >= P) return;

    const long b0 = (long)p * 32;              // pillar's first float4

    // 4 independent NT loads per lane; per instruction a wave covers
    // 8 x 128B full-line segments. NT keeps the 327MB stream out of L2/L3
    // so the zeroed canvas stays cache-resident for the scatter below.
    vfloat4 v0 = __builtin_nontemporal_load(&pillars4[b0 + r]);
    vfloat4 v1 = __builtin_nontemporal_load(&pillars4[b0 + r + 8]);
    vfloat4 v2 = __builtin_nontemporal_load(&pillars4[b0 + r + 16]);
    vfloat4 v3 = __builtin_nontemporal_load(&pillars4[b0 + r + 24]);
    __builtin_nontemporal_store(v0, &out_pillars4[b0 + r]);
    __builtin_nontemporal_store(v1, &out_pillars4[b0 + r + 8]);
    __builtin_nontemporal_store(v2, &out_pillars4[b0 + r + 16]);
    __builtin_nontemporal_store(v3, &out_pillars4[b0 + r + 24]);

    // Local 4-way add, then 3-step butterfly within the 8-lane group
    // (xor masks < 8 stay inside the group on wave64): 9 DS ops per 4KB wave.
    float sx = (v0.x + v1.x) + (v2.x + v3.x);
    float sy = (v0.y + v1.y) + (v2.y + v3.y);
    float sz = (v0.z + v1.z) + (v2.z + v3.z);
    #pragma unroll
    for (int m = 4; m >= 1; m >>= 1) {
        sx += __shfl_xor(sx, m);
        sy += __shfl_xor(sy, m);
        sz += __shfl_xor(sz, m);
    }

    if (r < 3) {
        // 24 active lanes/wave; coors4[p]: one 16B addr per group (broadcast).
        const int4 c   = coors4[p];
        const int npts = npoints[p];
        const float s  = (r == 0) ? sx : (r == 1) ? sy : sz;
        const float val = s / (float)npts;

        const int x_l = *xlp;
        const int y_l = *ylp;
        const long cs   = (long)y_l * (long)x_l;           // plane stride
        const long base = (long)c.x * 3l * cs + (long)c.z * (long)x_l + (long)c.y;
        canvas[base + (long)r * cs] = val;                 // plane r via lane r

        if (r == 0) {
            // 32 groups: out_coors4[p] consecutive within block -> contiguous.
            out_coors4[p] = make_float4((float)c.x, (float)c.y, (float)c.z, (float)c.w);
            out_np[p]     = (float)npts;
        }
    }
}

extern "C" void kernel_launch(void* const* d_in, const int* in_sizes, int n_in,
                              void* d_out, int out_size, void* d_ws, size_t ws_size,
                              hipStream_t stream) {
    const vfloat4* pillars4 = (const vfloat4*)d_in[0];
    const int4* coors4      = (const int4*)d_in[1];
    const int* npoints      = (const int*)d_in[2];
    const int* xlp = (const int*)d_in[4];
    const int* ylp = (const int*)d_in[5];

    const int n_pillars = in_sizes[0];   // P*128
    const int n_coors   = in_sizes[1];   // P*4
    const int P         = in_sizes[2];   // pillar count

    float* out            = (float*)d_out;
    vfloat4* out_pillars4 = (vfloat4*)out;
    float* out_coors      = out + n_pillars;
    float* out_np         = out_coors + n_coors;
    float* canvas         = out_np + P;
    const long canvas_elems = (long)out_size - n_pillars - n_coors - P;  // bs*3*y_l*x_l

    // K1: zero canvas (cacheable -> L3 resident for the scatter RMW).
    const long n4 = canvas_elems >> 2;   // canvas start is 16B-aligned here
    int zblocks = (int)((n4 + 511) / 512);
    if (zblocks > 2048) zblocks = 2048;
    canvas_zero<<<zblocks, 256, 0, stream>>>((float4*)canvas, n4);

    // K2: fused copy + reduce + scatter. 32 pillars per 256-thread block.
    const int blocks = (P + 31) / 32;
    pillar_fused<<<blocks, 256, 0, stream>>>(
        pillars4, coors4, npoints, xlp, ylp,
        out_pillars4, (float4*)out_coors, out_np, canvas, P);
}

// Round 13
// 72.061 us; speedup vs baseline: 1.0041x; 1.0041x over previous
//
#include <hip/hip_runtime.h>

// PillarLayer: fused copy + per-pillar xyz center-of-mass + BEV canvas scatter.
//
// R13 = R11 (best, 72.1us) with ONE change: out_pillars stores are CACHEABLE
// (writeback) instead of non-temporal; loads remain NT.
// A/B theory: K2 runs at ~5.2 TB/s vs the 6.29 TB/s cacheable-copy ceiling.
// The 7.0-7.2 TB/s fills and the 6.29 copy ceiling are both cacheable-write
// paths; NT write-through may not merge into full-line HBM bursts as well.
// NT loads still keep the 163MB read stream from evicting the L3-resident
// zeroed canvas (cost of store-side eviction: ~1-2us of refetch, accepted).
//
// Inputs: d_in[0] pillars f32 (P,32,4); d_in[1] coors int32 (P,4) [b,x,y,z];
//         d_in[2] npoints int32 (P); d_in[3] bs; d_in[4] x_l; d_in[5] y_l.
// Output (concat f32): pillars copy | coors as f32 | npoints as f32 |
//         canvas (bs,3,y_l,x_l) with canvas[b][c][y][x] = center_c or 0.

typedef float vfloat4 __attribute__((ext_vector_type(4)));

__global__ __launch_bounds__(256) void canvas_zero(float4* __restrict__ dst, long n4) {
    long i = (long)blockIdx.x * blockDim.x + threadIdx.x;
    const long stride = (long)gridDim.x * blockDim.x;
    const float4 z = make_float4(0.f, 0.f, 0.f, 0.f);
    for (; i < n4; i += stride) dst[i] = z;   // cacheable: L3-resident for scatter
}

__global__ __launch_bounds__(256) void pillar_fused(
    const vfloat4* __restrict__ pillars4,  // P*32 (one float4 per point)
    const int4* __restrict__ coors4,       // P [b,x,y,z]
    const int* __restrict__ npoints,       // P
    const int* __restrict__ xlp,           // scalar x_l
    const int* __restrict__ ylp,           // scalar y_l
    vfloat4* __restrict__ out_pillars4,    // P*32
    float4* __restrict__ out_coors4,       // P
    float* __restrict__ out_np,            // P
    float* __restrict__ canvas,            // bs*3*y_l*x_l
    int P)
{
    const int tid  = threadIdx.x;
    const int g    = tid >> 4;                 // pillar group within block (0..15)
    const int r    = tid & 15;                 // lane within pillar
    const int p    = blockIdx.x * 16 + g;      // pillar id (16 pillars/block)
    if (p >= P) return;

    const long b0 = (long)p * 32;              // pillar's first float4

    // Loads NT (read-once, keep L3 for the zeroed canvas); per instruction a
    // wave covers 4 x 256B full-line segments.
    const vfloat4 v0 = __builtin_nontemporal_load(&pillars4[b0 + r]);
    const vfloat4 v1 = __builtin_nontemporal_load(&pillars4[b0 + r + 16]);
    // Stores CACHEABLE (writeback merges full lines at HBM).
    out_pillars4[b0 + r]      = v0;
    out_pillars4[b0 + r + 16] = v1;

    // Local pair-add then 4-step butterfly within the 16-lane group
    // (xor masks < 16 stay inside the group on wave64): 12 DS ops/wave/2KB.
    float sx = v0.x + v1.x, sy = v0.y + v1.y, sz = v0.z + v1.z;
    #pragma unroll
    for (int m = 8; m >= 1; m >>= 1) {
        sx += __shfl_xor(sx, m);
        sy += __shfl_xor(sy, m);
        sz += __shfl_xor(sz, m);
    }

    if (r < 3) {
        // 12 active lanes/wave; coors4[p]: 4 distinct 16B addrs (broadcast per group).
        const int4 c   = coors4[p];
        const int npts = npoints[p];
        const float s  = (r == 0) ? sx : (r == 1) ? sy : sz;
        const float val = s / (float)npts;

        const int x_l = *xlp;
        const int y_l = *ylp;
        const long cs   = (long)y_l * (long)x_l;           // plane stride
        const long base = (long)c.x * 3l * cs + (long)c.z * (long)x_l + (long)c.y;
        canvas[base + (long)r * cs] = val;                 // plane r via lane r

        if (r == 0) {
            out_coors4[p] = make_float4((float)c.x, (float)c.y, (float)c.z, (float)c.w);
            out_np[p]     = (float)npts;
        }
    }
}

extern "C" void kernel_launch(void* const* d_in, const int* in_sizes, int n_in,
                              void* d_out, int out_size, void* d_ws, size_t ws_size,
                              hipStream_t stream) {
    const vfloat4* pillars4 = (const vfloat4*)d_in[0];
    const int4* coors4      = (const int4*)d_in[1];
    const int* npoints      = (const int*)d_in[2];
    const int* xlp = (const int*)d_in[4];
    const int* ylp = (const int*)d_in[5];

    const int n_pillars = in_sizes[0];   // P*128
    const int n_coors   = in_sizes[1];   // P*4
    const int P         = in_sizes[2];   // pillar count

    float* out            = (float*)d_out;
    vfloat4* out_pillars4 = (vfloat4*)out;
    float* out_coors      = out + n_pillars;
    float* out_np         = out_coors + n_coors;
    float* canvas         = out_np + P;
    const long canvas_elems = (long)out_size - n_pillars - n_coors - P;  // bs*3*y_l*x_l

    // K1: zero canvas (cacheable -> L3 resident for the scatter RMW).
    const long n4 = canvas_elems >> 2;   // canvas start is 16B-aligned here
    int zblocks = (int)((n4 + 511) / 512);
    if (zblocks > 2048) zblocks = 2048;
    canvas_zero<<<zblocks, 256, 0, stream>>>((float4*)canvas, n4);

    // K2: fused copy + reduce + scatter. 16 pillars per 256-thread block.
    const int blocks = (P + 15) / 16;
    pillar_fused<<<blocks, 256, 0, stream>>>(
        pillars4, coors4, npoints, xlp, ylp,
        out_pillars4, (float4*)out_coors, out_np, canvas, P);
}